// Round 10
// baseline (8847.914 us; speedup 1.0000x reference)
//
#include <hip/hip_runtime.h>

// SimpleRNN on MI355X — round 10: AGPR-pinned weights + all-builtin MFMA.
// B=256, S=512, I=128, H=512, O=128; fp32 in/out, f16 MFMA internally.
//
// r8 (all-builtin, passed 0.0078) spilled ~160 weight regs to scratch ->
// ~10k cy/step of L2 spill reloads. r9 (inline-asm MFMA) hit sporadic
// corruption (0.23) — compiler can't insert MFMA hazard waits around
// opaque asm. This round: builtins ONLY (compiler-managed hazards, the
// r8-proven path) + weights pinned into AGPRs via per-iteration
// asm("" : "+a") — asm-defined each iter => not rematerializable, and
// 256 AGPRs hold exactly 8 k-tiles, freeing the arch-VGPR file.
// kt 0..4 VGPR-pinned, 5..12 AGPR-pinned, 13..15 LDS (r8-proven).
// All formulas byte-identical to r8.

#define B_SZ 256
#define S_SZ 512
#define I_SZ 128
#define H_SZ 512
#define O_SZ 128

typedef _Float16 f16;
typedef _Float16 f16x8 __attribute__((ext_vector_type(8)));
typedef _Float16 f16x2 __attribute__((ext_vector_type(2)));
typedef float f32x4 __attribute__((ext_vector_type(4)));

__device__ __forceinline__ f16x8 cvt8(float4 a, float4 b) {
    f16x8 r;
    f16x2 p;
    p = __builtin_bit_cast(f16x2, __builtin_amdgcn_cvt_pkrtz(a.x, a.y)); r[0] = p[0]; r[1] = p[1];
    p = __builtin_bit_cast(f16x2, __builtin_amdgcn_cvt_pkrtz(a.z, a.w)); r[2] = p[0]; r[3] = p[1];
    p = __builtin_bit_cast(f16x2, __builtin_amdgcn_cvt_pkrtz(b.x, b.y)); r[4] = p[0]; r[5] = p[1];
    p = __builtin_bit_cast(f16x2, __builtin_amdgcn_cvt_pkrtz(b.z, b.w)); r[6] = p[0]; r[7] = p[1];
    return r;
}

// xp[(s*256 + b)*512 + j] = x_s[b] . Wih[j] + bih[j] + bhh[j], f16, plain.
__global__ __launch_bounds__(256) void xp_prepass2(
    const float* __restrict__ x, const float* __restrict__ Wih,
    const float* __restrict__ bih, const float* __restrict__ bhh,
    f16* __restrict__ xp)
{
    const int s = blockIdx.x;
    const int tid = threadIdx.x, w = tid >> 6, lane = tid & 63;
    const int c = lane & 15, g = lane >> 4;

    f16x8 wxb[8][4];
#pragma unroll
    for (int nt = 0; nt < 8; ++nt)
#pragma unroll
        for (int kx = 0; kx < 4; ++kx) {
            const float* src = Wih + (size_t)(w * 128 + nt * 16 + c) * I_SZ + kx * 32 + g * 8;
            wxb[nt][kx] = cvt8(*(const float4*)src, *(const float4*)(src + 4));
        }
    float bs[8];
#pragma unroll
    for (int nt = 0; nt < 8; ++nt)
        bs[nt] = bih[w * 128 + nt * 16 + c] + bhh[w * 128 + nt * 16 + c];

    for (int team = 0; team < 16; ++team) {
        f16x8 ax[4];
#pragma unroll
        for (int kx = 0; kx < 4; ++kx) {
            const float* src = x + ((size_t)(team * 16 + c) * S_SZ + s) * I_SZ + kx * 32 + g * 8;
            ax[kx] = cvt8(*(const float4*)src, *(const float4*)(src + 4));
        }
        f32x4 acc[8];
#pragma unroll
        for (int nt = 0; nt < 8; ++nt) acc[nt] = (f32x4){0.f, 0.f, 0.f, 0.f};
#pragma unroll
        for (int kx = 0; kx < 4; ++kx)
#pragma unroll
            for (int nt = 0; nt < 8; ++nt)
                acc[nt] = __builtin_amdgcn_mfma_f32_16x16x32_f16(ax[kx], wxb[nt][kx], acc[nt], 0, 0, 0);

        f16* dst = xp + ((size_t)s * B_SZ + (size_t)team * 16) * H_SZ;
#pragma unroll
        for (int nt = 0; nt < 8; ++nt) {
            int col = w * 128 + nt * 16 + c;
#pragma unroll
            for (int r = 0; r < 4; ++r)
                dst[(size_t)(g * 4 + r) * H_SZ + col] = (f16)(acc[nt][r] + bs[nt]);
        }
    }
}

// rnn_team5: one WG per 16 batch rows. LDS 122,880 B (r8-proven size).
__global__ __launch_bounds__(256, 1) void rnn_team5(
    const float* __restrict__ Whh, const f16* __restrict__ xp,
    f16* __restrict__ hout)
{
    __shared__ f16 wlds[512 * 104];   // 106,496 B : W_hh[j][k=416..511]
    __shared__ f16 hst[16 * 512];     //  16,384 B : h, single buffer, swizzled

    const int team = blockIdx.x;
    const int tid = threadIdx.x, w = tid >> 6, lane = tid & 63;
    const int c = lane & 15, g = lane >> 4;
    const int bt = team * 16;

    // stage W_hh k=416..511 (row stride 104 f16 = 208 B) — r8-proven
    for (int rr = 0; rr < 2; ++rr) {
        int row = tid * 2 + rr;
        const float* src = Whh + (size_t)row * H_SZ + 416;
#pragma unroll
        for (int i = 0; i < 96; i += 8)
            *(f16x8*)(wlds + row * 104 + i) =
                cvt8(*(const float4*)(src + i), *(const float4*)(src + i + 4));
    }

    // kt 0..4: VGPR-resident fragments (160 regs)
    f16x8 wb[8][5];
#pragma unroll
    for (int nt = 0; nt < 8; ++nt)
#pragma unroll
        for (int kt = 0; kt < 5; ++kt) {
            const float* src = Whh + (size_t)(w * 128 + nt * 16 + c) * H_SZ + kt * 32 + g * 8;
            wb[nt][kt] = cvt8(*(const float4*)src, *(const float4*)(src + 4));
        }

    // kt 5..12: AGPR-resident fragments (256 AGPRs exactly)
    f16x8 wa[8][8];
#pragma unroll
    for (int nt = 0; nt < 8; ++nt)
#pragma unroll
        for (int q = 0; q < 8; ++q) {
            const float* src = Whh + (size_t)(w * 128 + nt * 16 + c) * H_SZ + (5 + q) * 32 + g * 8;
            wa[nt][q] = cvt8(*(const float4*)src, *(const float4*)(src + 4));
            asm volatile("" : "+a"(wa[nt][q]));   // initial placement into AGPR
        }
    __syncthreads();

    for (int s = 0; s < S_SZ; ++s) {
        // xp for this step (plain layout, r8-proven); issued early, used late
        const f16* xs = xp + ((size_t)s * B_SZ + bt) * H_SZ;
        float xv[8][4];
#pragma unroll
        for (int nt = 0; nt < 8; ++nt)
#pragma unroll
            for (int r = 0; r < 4; ++r)
                xv[nt][r] = (float)xs[(size_t)(g * 4 + r) * H_SZ + w * 128 + nt * 16 + c];

        f32x4 acc[8];
#pragma unroll
        for (int nt = 0; nt < 8; ++nt) acc[nt] = (f32x4){0.f, 0.f, 0.f, 0.f};

        if (s > 0) {
            // Re-pin weights THIS iteration: asm-defined values cannot be
            // rematerialized; "a"/"v" classes keep them in-file. All MFMAs
            // below are builtins (compiler-managed hazards).
#pragma unroll
            for (int nt = 0; nt < 8; ++nt) {
#pragma unroll
                for (int kt = 0; kt < 5; ++kt) asm("" : "+v"(wb[nt][kt]));
#pragma unroll
                for (int q = 0; q < 8; ++q)    asm("" : "+a"(wa[nt][q]));
            }

            // kt 0..4 (VGPR weights)
#pragma unroll
            for (int kt = 0; kt < 5; ++kt) {
                f16x8 ah = *(const f16x8*)(hst + c * 512 + ((kt * 4 + g) ^ (c & 7)) * 8);
#pragma unroll
                for (int nt = 0; nt < 8; ++nt)
                    acc[nt] = __builtin_amdgcn_mfma_f32_16x16x32_f16(ah, wb[nt][kt], acc[nt], 0, 0, 0);
            }
            // kt 5..12 (AGPR weights — builtin binds av-class operand)
#pragma unroll
            for (int q = 0; q < 8; ++q) {
                int kt = 5 + q;
                f16x8 ah = *(const f16x8*)(hst + c * 512 + ((kt * 4 + g) ^ (c & 7)) * 8);
#pragma unroll
                for (int nt = 0; nt < 8; ++nt)
                    acc[nt] = __builtin_amdgcn_mfma_f32_16x16x32_f16(ah, wa[nt][q], acc[nt], 0, 0, 0);
            }
            // kt 13..15 (LDS weights, r8-proven)
#pragma unroll
            for (int kt = 13; kt < 16; ++kt) {
                f16x8 ah = *(const f16x8*)(hst + c * 512 + ((kt * 4 + g) ^ (c & 7)) * 8);
#pragma unroll
                for (int nt = 0; nt < 8; ++nt) {
                    f16x8 wv = *(const f16x8*)(wlds + (w * 128 + nt * 16 + c) * 104
                                               + (kt - 13) * 32 + g * 8);
                    acc[nt] = __builtin_amdgcn_mfma_f32_16x16x32_f16(ah, wv, acc[nt], 0, 0, 0);
                }
            }
        }
        __syncthreads();   // all hst reads of h(s) complete

        // tanh(acc + xp) -> r3/r8-proven writer: row=4g+r, col^((row&7)<<3)
#pragma unroll
        for (int nt = 0; nt < 8; ++nt) {
            int col = w * 128 + nt * 16 + c;
#pragma unroll
            for (int r = 0; r < 4; ++r) {
                float pre = acc[nt][r] + xv[nt][r];
                float e = __expf(2.f * pre);
                float hv = 1.f - 2.f * __builtin_amdgcn_rcpf(e + 1.f);
                int row = g * 4 + r;
                hst[row * 512 + (col ^ ((row & 7) << 3))] = (f16)hv;
                if (s == S_SZ - 1)
                    hout[(size_t)(bt + row) * H_SZ + col] = (f16)hv;
            }
        }
        __syncthreads();   // h(s+1) visible for next step
    }
}

// out[b][o] = sum_k h[b][k] * Wfc[o][k] + bfc[o]
__global__ __launch_bounds__(128) void fc_kernel(
    const f16* __restrict__ hbuf, const float* __restrict__ Wfc,
    const float* __restrict__ bfc, float* __restrict__ out)
{
    __shared__ float hs[H_SZ];
    int b = blockIdx.x, o = threadIdx.x;
    for (int k = o; k < H_SZ; k += 128)
        hs[k] = (float)hbuf[(size_t)b * H_SZ + k];
    __syncthreads();
    const float* wr = Wfc + (size_t)o * H_SZ;
    float acc = bfc[o];
#pragma unroll 8
    for (int k = 0; k < H_SZ; k += 4) {
        float4 wv = *(const float4*)(wr + k);
        acc += wv.x * hs[k] + wv.y * hs[k + 1] + wv.z * hs[k + 2] + wv.w * hs[k + 3];
    }
    out[(size_t)b * O_SZ + o] = acc;
}

extern "C" void kernel_launch(void* const* d_in, const int* in_sizes, int n_in,
                              void* d_out, int out_size, void* d_ws, size_t ws_size,
                              hipStream_t stream) {
    const float* x   = (const float*)d_in[0];
    const float* Wih = (const float*)d_in[1];
    const float* Whh = (const float*)d_in[2];
    const float* bih = (const float*)d_in[3];
    const float* bhh = (const float*)d_in[4];
    const float* Wfc = (const float*)d_in[5];
    const float* bfc = (const float*)d_in[6];
    float* out = (float*)d_out;

    // ws layout: hout (256 KB) at 0; xp plain f16 [s][b][j] (128 MiB) at 1 MiB.
    f16* hout = (f16*)d_ws;
    f16* xp   = (f16*)((char*)d_ws + ((size_t)1 << 20));

    hipLaunchKernelGGL(xp_prepass2, dim3(S_SZ), dim3(256), 0, stream,
                       x, Wih, bih, bhh, xp);
    hipLaunchKernelGGL(rnn_team5, dim3(16), dim3(256), 0, stream,
                       Whh, xp, hout);
    hipLaunchKernelGGL(fc_kernel, dim3(B_SZ), dim3(128), 0, stream,
                       hout, Wfc, bfc, out);
}

// Round 11
// 2551.887 us; speedup vs baseline: 3.4672x; 3.4672x over previous
//
#include <hip/hip_runtime.h>

// SimpleRNN on MI355X — round 11: AGPR-exact weights + L2-streamed remainder.
// B=256, S=512, I=128, H=512, O=128; fp32 in/out, f16 MFMA internally.
//
// Register-file arithmetic (lesson of r8-r10): MFMA B-operands can live in
// AGPRs (256/lane) but acc/addresses/stream buffers must be VGPRs (256/lane).
//   kt 0..7   -> 256 AGPRs exactly (pinned ONCE; r10 proved init-pins+builtin
//                MFMA correct; r10's slowdown was per-iteration RE-pins).
//   kt 8..12  -> streamed per step from wstream (f16, fragment-ordered,
//                idx-major so lanes are consecutive dwordx4; 160 KB,
//                L2-resident; double-buffered sA/sB, static names).
//   kt 13..15 -> LDS wlds [512][104] (r8-proven staging).
// VGPR demand ~180 <= 256 -> no scratch spill. All math formulas / swizzles /
// xp handoff byte-identical to r8 (passed, absmax 0.0078).

#define B_SZ 256
#define S_SZ 512
#define I_SZ 128
#define H_SZ 512
#define O_SZ 128

typedef _Float16 f16;
typedef _Float16 f16x8 __attribute__((ext_vector_type(8)));
typedef _Float16 f16x2 __attribute__((ext_vector_type(2)));
typedef float f32x4 __attribute__((ext_vector_type(4)));

__device__ __forceinline__ f16x8 cvt8(float4 a, float4 b) {
    f16x8 r;
    f16x2 p;
    p = __builtin_bit_cast(f16x2, __builtin_amdgcn_cvt_pkrtz(a.x, a.y)); r[0] = p[0]; r[1] = p[1];
    p = __builtin_bit_cast(f16x2, __builtin_amdgcn_cvt_pkrtz(a.z, a.w)); r[2] = p[0]; r[3] = p[1];
    p = __builtin_bit_cast(f16x2, __builtin_amdgcn_cvt_pkrtz(b.x, b.y)); r[4] = p[0]; r[5] = p[1];
    p = __builtin_bit_cast(f16x2, __builtin_amdgcn_cvt_pkrtz(b.z, b.w)); r[6] = p[0]; r[7] = p[1];
    return r;
}

// wstream: kt 8..12 of W_hh as f16 fragments, idx-major.
// idx = (kt-8)*8 + nt; elem addr = (idx*256 + tid)*8 .. +8.
// Fragment content matches r8's wb formula for (w,c,g) = tid decomposition.
__global__ __launch_bounds__(256) void wcvt_prepass(
    const float* __restrict__ Whh, f16* __restrict__ wstream)
{
    const int t = threadIdx.x;
    const int w = t >> 6, lane = t & 63, c = lane & 15, g = lane >> 4;
    for (int idx = 0; idx < 40; ++idx) {
        int kt = 8 + (idx >> 3), nt = idx & 7;
        const float* src = Whh + (size_t)(w * 128 + nt * 16 + c) * H_SZ + kt * 32 + g * 8;
        *(f16x8*)(wstream + ((size_t)idx * 256 + t) * 8) =
            cvt8(*(const float4*)src, *(const float4*)(src + 4));
    }
}

// xp[(s*256 + b)*512 + j] = x_s[b] . Wih[j] + bih[j] + bhh[j], f16, plain. (r8)
__global__ __launch_bounds__(256) void xp_prepass2(
    const float* __restrict__ x, const float* __restrict__ Wih,
    const float* __restrict__ bih, const float* __restrict__ bhh,
    f16* __restrict__ xp)
{
    const int s = blockIdx.x;
    const int tid = threadIdx.x, w = tid >> 6, lane = tid & 63;
    const int c = lane & 15, g = lane >> 4;

    f16x8 wxb[8][4];
#pragma unroll
    for (int nt = 0; nt < 8; ++nt)
#pragma unroll
        for (int kx = 0; kx < 4; ++kx) {
            const float* src = Wih + (size_t)(w * 128 + nt * 16 + c) * I_SZ + kx * 32 + g * 8;
            wxb[nt][kx] = cvt8(*(const float4*)src, *(const float4*)(src + 4));
        }
    float bs[8];
#pragma unroll
    for (int nt = 0; nt < 8; ++nt)
        bs[nt] = bih[w * 128 + nt * 16 + c] + bhh[w * 128 + nt * 16 + c];

    for (int team = 0; team < 16; ++team) {
        f16x8 ax[4];
#pragma unroll
        for (int kx = 0; kx < 4; ++kx) {
            const float* src = x + ((size_t)(team * 16 + c) * S_SZ + s) * I_SZ + kx * 32 + g * 8;
            ax[kx] = cvt8(*(const float4*)src, *(const float4*)(src + 4));
        }
        f32x4 acc[8];
#pragma unroll
        for (int nt = 0; nt < 8; ++nt) acc[nt] = (f32x4){0.f, 0.f, 0.f, 0.f};
#pragma unroll
        for (int kx = 0; kx < 4; ++kx)
#pragma unroll
            for (int nt = 0; nt < 8; ++nt)
                acc[nt] = __builtin_amdgcn_mfma_f32_16x16x32_f16(ax[kx], wxb[nt][kx], acc[nt], 0, 0, 0);

        f16* dst = xp + ((size_t)s * B_SZ + (size_t)team * 16) * H_SZ;
#pragma unroll
        for (int nt = 0; nt < 8; ++nt) {
            int col = w * 128 + nt * 16 + c;
#pragma unroll
            for (int r = 0; r < 4; ++r)
                dst[(size_t)(g * 4 + r) * H_SZ + col] = (f16)(acc[nt][r] + bs[nt]);
        }
    }
}

__device__ __forceinline__ void loadk(f16x8 (&buf)[8], const f16* __restrict__ wstream,
                                      int kt, int tid) {
#pragma unroll
    for (int nt = 0; nt < 8; ++nt)
        buf[nt] = *(const f16x8*)(wstream + ((size_t)((kt - 8) * 8 + nt) * 256 + tid) * 8);
}

__device__ __forceinline__ void mfmak(f32x4 (&acc)[8], f16x8 ah, const f16x8 (&buf)[8]) {
#pragma unroll
    for (int nt = 0; nt < 8; ++nt)
        acc[nt] = __builtin_amdgcn_mfma_f32_16x16x32_f16(ah, buf[nt], acc[nt], 0, 0, 0);
}

// rnn_team6: one WG per 16 batch rows. LDS 122,880 B (r8-proven size).
__global__ __launch_bounds__(256, 1) void rnn_team6(
    const float* __restrict__ Whh, const f16* __restrict__ wstream,
    const f16* __restrict__ xp, f16* __restrict__ hout)
{
    __shared__ f16 wlds[512 * 104];   // 106,496 B : W_hh[j][k=416..511]
    __shared__ f16 hst[16 * 512];     //  16,384 B : h, single buffer, swizzled

    const int team = blockIdx.x;
    const int tid = threadIdx.x, w = tid >> 6, lane = tid & 63;
    const int c = lane & 15, g = lane >> 4;
    const int bt = team * 16;

    // stage W_hh k=416..511 into LDS (r8-proven)
    for (int rr = 0; rr < 2; ++rr) {
        int row = tid * 2 + rr;
        const float* src = Whh + (size_t)row * H_SZ + 416;
#pragma unroll
        for (int i = 0; i < 96; i += 8)
            *(f16x8*)(wlds + row * 104 + i) =
                cvt8(*(const float4*)(src + i), *(const float4*)(src + i + 4));
    }

    // kt 0..7: weight fragments -> AGPRs (exactly 256), pinned ONCE.
    f16x8 wb[8][8];   // [nt][kt]
#pragma unroll
    for (int nt = 0; nt < 8; ++nt)
#pragma unroll
        for (int kt = 0; kt < 8; ++kt) {
            const float* src = Whh + (size_t)(w * 128 + nt * 16 + c) * H_SZ + kt * 32 + g * 8;
            wb[nt][kt] = cvt8(*(const float4*)src, *(const float4*)(src + 4));
            asm volatile("" : "+a"(wb[nt][kt]));   // one-time AGPR placement
        }
    __syncthreads();

    for (int s = 0; s < S_SZ; ++s) {
        // xp loads (plain layout, r8-proven); issued early, consumed at tanh
        const f16* xs = xp + ((size_t)s * B_SZ + bt) * H_SZ;
        float xv[8][4];
#pragma unroll
        for (int nt = 0; nt < 8; ++nt)
#pragma unroll
            for (int r = 0; r < 4; ++r)
                xv[nt][r] = (float)xs[(size_t)(g * 4 + r) * H_SZ + w * 128 + nt * 16 + c];

        f32x4 acc[8];
#pragma unroll
        for (int nt = 0; nt < 8; ++nt) acc[nt] = (f32x4){0.f, 0.f, 0.f, 0.f};

        if (s > 0) {
            f16x8 sA[8], sB[8];
            loadk(sA, wstream, 8, tid);     // in flight across reg-kt MFMAs
            loadk(sB, wstream, 9, tid);

            // kt 0..7 from AGPR-resident weights (builtin MFMA)
#pragma unroll
            for (int kt = 0; kt < 8; ++kt) {
                f16x8 ah = *(const f16x8*)(hst + c * 512 + ((kt * 4 + g) ^ (c & 7)) * 8);
#pragma unroll
                for (int nt = 0; nt < 8; ++nt)
                    acc[nt] = __builtin_amdgcn_mfma_f32_16x16x32_f16(ah, wb[nt][kt], acc[nt], 0, 0, 0);
            }
            // kt 8..12 streamed, 2-deep rotation (static buffer names)
            {
                f16x8 ah;
                ah = *(const f16x8*)(hst + c * 512 + ((8 * 4 + g) ^ (c & 7)) * 8);
                mfmak(acc, ah, sA);
                loadk(sA, wstream, 10, tid);
                ah = *(const f16x8*)(hst + c * 512 + ((9 * 4 + g) ^ (c & 7)) * 8);
                mfmak(acc, ah, sB);
                loadk(sB, wstream, 11, tid);
                ah = *(const f16x8*)(hst + c * 512 + ((10 * 4 + g) ^ (c & 7)) * 8);
                mfmak(acc, ah, sA);
                loadk(sA, wstream, 12, tid);
                ah = *(const f16x8*)(hst + c * 512 + ((11 * 4 + g) ^ (c & 7)) * 8);
                mfmak(acc, ah, sB);
                ah = *(const f16x8*)(hst + c * 512 + ((12 * 4 + g) ^ (c & 7)) * 8);
                mfmak(acc, ah, sA);
            }
            // kt 13..15 from LDS (r8-proven)
#pragma unroll
            for (int kt = 13; kt < 16; ++kt) {
                f16x8 ah = *(const f16x8*)(hst + c * 512 + ((kt * 4 + g) ^ (c & 7)) * 8);
#pragma unroll
                for (int nt = 0; nt < 8; ++nt) {
                    f16x8 wv = *(const f16x8*)(wlds + (w * 128 + nt * 16 + c) * 104
                                               + (kt - 13) * 32 + g * 8);
                    acc[nt] = __builtin_amdgcn_mfma_f32_16x16x32_f16(ah, wv, acc[nt], 0, 0, 0);
                }
            }
        }
        __syncthreads();   // all hst reads of h(s) complete

        // tanh(acc + xp) -> r3/r8-proven writer: row=4g+r, col^((row&7)<<3)
#pragma unroll
        for (int nt = 0; nt < 8; ++nt) {
            int col = w * 128 + nt * 16 + c;
#pragma unroll
            for (int r = 0; r < 4; ++r) {
                float pre = acc[nt][r] + xv[nt][r];
                float e = __expf(2.f * pre);
                float hv = 1.f - 2.f * __builtin_amdgcn_rcpf(e + 1.f);
                int row = g * 4 + r;
                hst[row * 512 + (col ^ ((row & 7) << 3))] = (f16)hv;
                if (s == S_SZ - 1)
                    hout[(size_t)(bt + row) * H_SZ + col] = (f16)hv;
            }
        }
        __syncthreads();   // h(s+1) visible for next step
    }
}

// out[b][o] = sum_k h[b][k] * Wfc[o][k] + bfc[o]
__global__ __launch_bounds__(128) void fc_kernel(
    const f16* __restrict__ hbuf, const float* __restrict__ Wfc,
    const float* __restrict__ bfc, float* __restrict__ out)
{
    __shared__ float hs[H_SZ];
    int b = blockIdx.x, o = threadIdx.x;
    for (int k = o; k < H_SZ; k += 128)
        hs[k] = (float)hbuf[(size_t)b * H_SZ + k];
    __syncthreads();
    const float* wr = Wfc + (size_t)o * H_SZ;
    float acc = bfc[o];
#pragma unroll 8
    for (int k = 0; k < H_SZ; k += 4) {
        float4 wv = *(const float4*)(wr + k);
        acc += wv.x * hs[k] + wv.y * hs[k + 1] + wv.z * hs[k + 2] + wv.w * hs[k + 3];
    }
    out[(size_t)b * O_SZ + o] = acc;
}

extern "C" void kernel_launch(void* const* d_in, const int* in_sizes, int n_in,
                              void* d_out, int out_size, void* d_ws, size_t ws_size,
                              hipStream_t stream) {
    const float* x   = (const float*)d_in[0];
    const float* Wih = (const float*)d_in[1];
    const float* Whh = (const float*)d_in[2];
    const float* bih = (const float*)d_in[3];
    const float* bhh = (const float*)d_in[4];
    const float* Wfc = (const float*)d_in[5];
    const float* bfc = (const float*)d_in[6];
    float* out = (float*)d_out;

    // ws: hout 256KB @0; wstream 160KB @512KB; xp 128MiB @1MiB.
    f16* hout    = (f16*)d_ws;
    f16* wstream = (f16*)((char*)d_ws + (512 << 10));
    f16* xp      = (f16*)((char*)d_ws + ((size_t)1 << 20));

    hipLaunchKernelGGL(wcvt_prepass, dim3(1), dim3(256), 0, stream, Whh, wstream);
    hipLaunchKernelGGL(xp_prepass2, dim3(S_SZ), dim3(256), 0, stream,
                       x, Wih, bih, bhh, xp);
    hipLaunchKernelGGL(rnn_team6, dim3(16), dim3(256), 0, stream,
                       Whh, wstream, xp, hout);
    hipLaunchKernelGGL(fc_kernel, dim3(B_SZ), dim3(128), 0, stream,
                       hout, Wfc, bfc, out);
}